// Round 1
// baseline (148.305 us; speedup 1.0000x reference)
//
#include <hip/hip_runtime.h>
#include <cstdint>

#define FMAPX 188
#define NCELLS (FMAPX * FMAPX)   // 35344
#define KMAX 512
#define NCLS 3
#define IDX_INF 0x7fffffff

// ---------------------------------------------------------------------------
// Workspace layout (all fields written every launch before being read)
// ---------------------------------------------------------------------------
struct WS {
    float cxf[KMAX], cyf[KMAX];   // float (clipped) centers
    int   cix[KMAX], ciy[KMAX];   // int centers
    float a[KMAX];                // 1 / (2 sigma^2)
    int   valid[KMAX];
    int   seg[4];                 // class segment offsets into list[]
    int   list[KMAX];             // valid objects grouped by class
    int   dmin[KMAX];             // min integer squared distance
    int   ind[KMAX];              // argmin voxel index (first occurrence)
    float dminf[KMAX];            // (float)dmin
    float factor[KMAX];           // min(exp(-dmin*a)*1e6, 1)
    int   minidx[NCELLS];         // per-cell smallest voxel index (or IDX_INF)
    float H[NCLS][NCELLS];        // per-cell heatmap
};

// ---------------------------------------------------------------------------
// 1. init cell map
// ---------------------------------------------------------------------------
__global__ __launch_bounds__(256) void k_init_map(WS* ws) {
    int c = blockIdx.x * 256 + threadIdx.x;
    if (c < NCELLS) ws->minidx[c] = IDX_INF;
}

// 2. build per-cell min voxel index
__global__ __launch_bounds__(256) void k_build_map(const int* __restrict__ si, int N, WS* ws) {
    int n = blockIdx.x * 256 + threadIdx.x;
    if (n >= N) return;
    int2 v = ((const int2*)si)[n];
    int cell = v.x * FMAPX + v.y;
    atomicMin(&ws->minidx[cell], n);
}

// 3. per-object setup + class bucketing (single block)
__global__ __launch_bounds__(KMAX) void k_objs(const float* __restrict__ gt, int K, WS* ws) {
    __shared__ int cnt[NCLS];
    __shared__ int off[NCLS];
    int t = threadIdx.x;
    if (t < NCLS) cnt[t] = 0;
    __syncthreads();

    int myrank = -1, mycls = -1;
    if (t < K) {
        const float* g = gt + t * 8;
        float x = g[0], y = g[1];
        float ddx = g[3], ddy = g[4];
        bool val = (ddx > 0.0f) && (ddy > 0.0f);

        float coord_x = (x - (-75.2f)) / 0.1f / 8.0f;
        coord_x = fminf(fmaxf(coord_x, 0.0f), (float)FMAPX - 0.5f);
        float coord_y = (y - (-75.2f)) / 0.1f / 8.0f;
        coord_y = fminf(fmaxf(coord_y, 0.0f), (float)FMAPX - 0.5f);

        float h = ddx / 0.1f / 8.0f;   // "dx" in reference = height arg
        float w = ddy / 0.1f / 8.0f;

        const float ov = 0.1f;
        float b1 = h + w;
        float c1 = w * h * (1.0f - ov) / (1.0f + ov);
        float r1 = (b1 + sqrtf(b1 * b1 - 4.0f * c1)) / 2.0f;
        float b2 = 2.0f * (h + w);
        float c2 = (1.0f - ov) * w * h;
        float r2 = (b2 + sqrtf(b2 * b2 - 16.0f * c2)) / 8.0f;
        float a3 = 4.0f * ov;
        float b3 = -2.0f * ov * (h + w);
        float c3 = (ov - 1.0f) * w * h;
        float r3 = (-b3 + sqrtf(b3 * b3 - 4.0f * a3 * c3)) / (2.0f * a3);
        float r = fminf(fminf(r1, r2), r3);
        int radius = (int)r;
        if (radius < 2) radius = 2;
        float sigma = (2.0f * (float)radius + 1.0f) / 6.0f;

        ws->cxf[t] = coord_x;
        ws->cyf[t] = coord_y;
        ws->cix[t] = (int)coord_x;
        ws->ciy[t] = (int)coord_y;
        ws->a[t]   = 1.0f / (2.0f * sigma * sigma);
        ws->valid[t] = val ? 1 : 0;

        mycls = (int)(g[7] - 1.0f);
        if (val && mycls >= 0 && mycls < NCLS)
            myrank = atomicAdd(&cnt[mycls], 1);
    }
    __syncthreads();
    if (t == 0) {
        off[0] = 0; off[1] = cnt[0]; off[2] = cnt[0] + cnt[1];
        ws->seg[0] = 0;
        ws->seg[1] = cnt[0];
        ws->seg[2] = cnt[0] + cnt[1];
        ws->seg[3] = cnt[0] + cnt[1] + cnt[2];
    }
    __syncthreads();
    if (myrank >= 0) ws->list[off[mycls] + myrank] = t;
}

// 4. per-object min-distance + first-index over occupied cells
__global__ __launch_bounds__(256) void k_argmin(WS* ws) {
    int k = blockIdx.x;
    int cix = ws->cix[k], ciy = ws->ciy[k];
    unsigned long long best = ~0ull;
    for (int c = threadIdx.x; c < NCELLS; c += 256) {
        int mi = ws->minidx[c];
        if (mi != IDX_INF) {
            int cx = c / FMAPX, cy = c - (c / FMAPX) * FMAPX;
            int dx = cx - cix, dy = cy - ciy;
            unsigned int d = (unsigned int)(dx * dx + dy * dy);
            unsigned long long key = ((unsigned long long)d << 32) | (unsigned int)mi;
            if (key < best) best = key;
        }
    }
    for (int o = 32; o > 0; o >>= 1) {
        unsigned long long other = __shfl_down(best, o, 64);
        if (other < best) best = other;
    }
    __shared__ unsigned long long wb[4];
    int lane = threadIdx.x & 63, wid = threadIdx.x >> 6;
    if (lane == 0) wb[wid] = best;
    __syncthreads();
    if (threadIdx.x == 0) {
        for (int i = 1; i < 4; i++)
            if (wb[i] < best) best = wb[i];
        ws->dmin[k] = (int)(best >> 32);
        ws->ind[k]  = (int)(best & 0xffffffffull);
    }
}

// 5. finalize ret_boxes / inds / valid + per-object norm factors
__global__ __launch_bounds__(KMAX) void k_final(const float* __restrict__ gt,
                                                const int* __restrict__ si,
                                                int K, int N, WS* ws,
                                                float* __restrict__ out) {
    int t = threadIdx.x;
    if (t >= K) return;
    int  val   = ws->valid[t];
    float a    = ws->a[t];
    float dminf = (float)ws->dmin[t];
    float e     = expf(-dminf * a);
    ws->dminf[t]  = dminf;
    ws->factor[t] = fminf(e * 1e6f, 1.0f);

    int ind = ws->ind[t];
    float nx = (float)si[2 * ind];
    float ny = (float)si[2 * ind + 1];
    const float* g = gt + t * 8;

    float* rb = out + 3 * N + t * 8;
    rb[0] = val ? (ws->cxf[t] - nx) : 0.0f;
    rb[1] = val ? (ws->cyf[t] - ny) : 0.0f;
    rb[2] = val ? g[2] : 0.0f;
    rb[3] = val ? logf(g[3]) : 0.0f;
    rb[4] = val ? logf(g[4]) : 0.0f;
    rb[5] = val ? logf(g[5]) : 0.0f;
    rb[6] = val ? cosf(g[6]) : 0.0f;
    rb[7] = val ? sinf(g[6]) : 0.0f;

    out[3 * N + 8 * K + t] = (float)ind;          // inds
    out[3 * N + 9 * K + t] = val ? 1.0f : 0.0f;   // valid
}

// 6. per-cell heatmap (object table in LDS, grouped by class)
__global__ __launch_bounds__(256) void k_heat(WS* ws) {
    __shared__ float cxL[KMAX], cyL[KMAX], aL[KMAX], dmL[KMAX], fcL[KMAX];
    __shared__ int segS[4];
    if (threadIdx.x < 4) segS[threadIdx.x] = ws->seg[threadIdx.x];
    __syncthreads();
    int ktot = segS[3];
    for (int i = threadIdx.x; i < ktot; i += 256) {
        int o = ws->list[i];
        cxL[i] = (float)ws->cix[o];
        cyL[i] = (float)ws->ciy[o];
        aL[i]  = ws->a[o];
        dmL[i] = ws->dminf[o];
        fcL[i] = ws->factor[o];
    }
    __syncthreads();

    int c = blockIdx.x * 256 + threadIdx.x;
    if (c >= NCELLS) return;
    float cx = (float)(c / FMAPX);
    float cy = (float)(c - (c / FMAPX) * FMAPX);

    float m0 = 0.0f, m1 = 0.0f, m2 = 0.0f;
    int s1 = segS[1], s2 = segS[2];
    for (int i = 0; i < s1; i++) {
        float dx = cx - cxL[i], dy = cy - cyL[i];
        float dist = fmaf(dx, dx, dy * dy);
        float gv = __expf((dmL[i] - dist) * aL[i]) * fcL[i];
        m0 = fmaxf(m0, gv);
    }
    for (int i = s1; i < s2; i++) {
        float dx = cx - cxL[i], dy = cy - cyL[i];
        float dist = fmaf(dx, dx, dy * dy);
        float gv = __expf((dmL[i] - dist) * aL[i]) * fcL[i];
        m1 = fmaxf(m1, gv);
    }
    for (int i = s2; i < ktot; i++) {
        float dx = cx - cxL[i], dy = cy - cyL[i];
        float dist = fmaf(dx, dx, dy * dy);
        float gv = __expf((dmL[i] - dist) * aL[i]) * fcL[i];
        m2 = fmaxf(m2, gv);
    }
    ws->H[0][c] = m0;
    ws->H[1][c] = m1;
    ws->H[2][c] = m2;
}

// 7. gather per-voxel heatmap
__global__ __launch_bounds__(256) void k_gather(const int* __restrict__ si, int N,
                                                const WS* __restrict__ ws,
                                                float* __restrict__ out) {
    int n = blockIdx.x * 256 + threadIdx.x;
    if (n >= N) return;
    int2 v = ((const int2*)si)[n];
    int c = v.x * FMAPX + v.y;
    out[n]         = ws->H[0][c];
    out[N + n]     = ws->H[1][c];
    out[2 * N + n] = ws->H[2][c];
}

// ---------------------------------------------------------------------------
extern "C" void kernel_launch(void* const* d_in, const int* in_sizes, int n_in,
                              void* d_out, int out_size, void* d_ws, size_t ws_size,
                              hipStream_t stream) {
    const float* gt = (const float*)d_in[0];
    const int*   si = (const int*)d_in[1];
    int K = in_sizes[0] / 8;     // 500
    int N = in_sizes[1] / 2;     // 150000
    WS* ws = (WS*)d_ws;
    float* out = (float*)d_out;

    hipLaunchKernelGGL(k_init_map, dim3((NCELLS + 255) / 256), dim3(256), 0, stream, ws);
    hipLaunchKernelGGL(k_build_map, dim3((N + 255) / 256), dim3(256), 0, stream, si, N, ws);
    hipLaunchKernelGGL(k_objs, dim3(1), dim3(KMAX), 0, stream, gt, K, ws);
    hipLaunchKernelGGL(k_argmin, dim3(K), dim3(256), 0, stream, ws);
    hipLaunchKernelGGL(k_final, dim3(1), dim3(KMAX), 0, stream, gt, si, K, N, ws, out);
    hipLaunchKernelGGL(k_heat, dim3((NCELLS + 255) / 256), dim3(256), 0, stream, ws);
    hipLaunchKernelGGL(k_gather, dim3((N + 255) / 256), dim3(256), 0, stream, si, N, ws, out);
}

// Round 2
// 104.458 us; speedup vs baseline: 1.4198x; 1.4198x over previous
//
#include <hip/hip_runtime.h>
#include <cstdint>

#define FMAPX 188
#define NCELLS (FMAPX * FMAPX)   // 35344
#define KMAX 512
#define NCLS 3
#define IDX_INIT 0x7f7f7f7f      // memset(0x7f) pattern; > any voxel index

// ---------------------------------------------------------------------------
// Workspace layout (all fields written every launch before being read)
// ---------------------------------------------------------------------------
struct WS {
    float cxi[KMAX], cyi[KMAX];   // (float)int centers (for k_heat)
    float a[KMAX];                // 1 / (2 sigma^2)
    int   seg[4];                 // class segment offsets into list[]
    int   list[KMAX];             // valid objects grouped by class
    float dminf[KMAX];            // (float)min squared distance
    float factor[KMAX];           // min(exp(-dmin*a)*1e6, 1)
    int   minidx[NCELLS];         // per-cell smallest voxel index (or IDX_INIT)
    float H[NCLS][NCELLS];        // per-cell heatmap
};

// ---------------------------------------------------------------------------
// 1. build per-cell min voxel index (minidx pre-initialized via memsetAsync)
// ---------------------------------------------------------------------------
__global__ __launch_bounds__(256) void k_build_map(const int* __restrict__ si, int N, WS* ws) {
    int n = blockIdx.x * 256 + threadIdx.x;
    if (n >= N) return;
    int2 v = ((const int2*)si)[n];
    int cell = v.x * FMAPX + v.y;
    atomicMin(&ws->minidx[cell], n);
}

// ---------------------------------------------------------------------------
// 2. per-object everything: setup + class bucketing + ring-search argmin +
//    ret_boxes/inds/valid outputs + heatmap normalization factors
// ---------------------------------------------------------------------------
__device__ __forceinline__ void scan_cell(const int* __restrict__ minidx,
                                          int x, int y, int cix, int ciy,
                                          unsigned long long& best) {
    int mi = minidx[x * FMAPX + y];
    if (mi != IDX_INIT) {
        int dx = x - cix, dy = y - ciy;
        unsigned int d = (unsigned int)(dx * dx + dy * dy);
        unsigned long long key = ((unsigned long long)d << 32) | (unsigned int)mi;
        if (key < best) best = key;
    }
}

__global__ __launch_bounds__(KMAX) void k_obj_all(const float* __restrict__ gt,
                                                  const int* __restrict__ si,
                                                  int K, int N, WS* ws,
                                                  float* __restrict__ out) {
    __shared__ int cnt[NCLS];
    __shared__ int off[NCLS];
    int t = threadIdx.x;
    if (t < NCLS) cnt[t] = 0;
    __syncthreads();

    int myrank = -1, mycls = -1;
    int cix = 0, ciy = 0, val = 0;
    float coord_x = 0.0f, coord_y = 0.0f, a = 0.0f;
    if (t < K) {
        const float* g = gt + t * 8;
        float ddx = g[3], ddy = g[4];
        val = ((ddx > 0.0f) && (ddy > 0.0f)) ? 1 : 0;

        coord_x = (g[0] + 75.2f) * (1.0f / 0.8f);
        coord_x = fminf(fmaxf(coord_x, 0.0f), (float)FMAPX - 0.5f);
        coord_y = (g[1] + 75.2f) * (1.0f / 0.8f);
        coord_y = fminf(fmaxf(coord_y, 0.0f), (float)FMAPX - 0.5f);
        cix = (int)coord_x;
        ciy = (int)coord_y;

        float h = ddx * (1.0f / 0.8f);   // reference: height arg = dx
        float w = ddy * (1.0f / 0.8f);

        const float ov = 0.1f;
        float b1 = h + w;
        float c1 = w * h * (1.0f - ov) / (1.0f + ov);
        float r1 = (b1 + sqrtf(b1 * b1 - 4.0f * c1)) * 0.5f;
        float b2 = 2.0f * (h + w);
        float c2 = (1.0f - ov) * w * h;
        float r2 = (b2 + sqrtf(b2 * b2 - 16.0f * c2)) * 0.125f;
        float a3 = 4.0f * ov;
        float b3 = -2.0f * ov * (h + w);
        float c3 = (ov - 1.0f) * w * h;
        float r3 = (-b3 + sqrtf(b3 * b3 - 4.0f * a3 * c3)) / (2.0f * a3);
        float r = fminf(fminf(r1, r2), r3);
        int radius = (int)r;
        if (radius < 2) radius = 2;
        float sigma = (2.0f * (float)radius + 1.0f) * (1.0f / 6.0f);
        a = 1.0f / (2.0f * sigma * sigma);

        ws->cxi[t] = (float)cix;
        ws->cyi[t] = (float)ciy;
        ws->a[t]   = a;

        mycls = (int)(g[7] - 1.0f);
        if (val && mycls >= 0 && mycls < NCLS)
            myrank = atomicAdd(&cnt[mycls], 1);
    }
    __syncthreads();
    if (t == 0) {
        off[0] = 0; off[1] = cnt[0]; off[2] = cnt[0] + cnt[1];
        ws->seg[0] = 0;
        ws->seg[1] = cnt[0];
        ws->seg[2] = cnt[0] + cnt[1];
        ws->seg[3] = cnt[0] + cnt[1] + cnt[2];
    }
    __syncthreads();
    if (myrank >= 0) ws->list[off[mycls] + myrank] = t;

    if (t >= K) return;

    // --- expanding-ring exact argmin over occupied cells ---
    const int* __restrict__ minidx = ws->minidx;
    unsigned long long best = ~0ull;
    for (int r = 0; r <= 2 * FMAPX; ++r) {
        if (best != ~0ull && (unsigned long long)r * (unsigned long long)r > (best >> 32)) break;
        if (r == 0) {
            scan_cell(minidx, cix, ciy, cix, ciy, best);
        } else {
            int x0 = cix - r, x1 = cix + r;
            int ylo = max(ciy - r, 0), yhi = min(ciy + r, FMAPX - 1);
            if (x0 >= 0)    for (int y = ylo; y <= yhi; ++y) scan_cell(minidx, x0, y, cix, ciy, best);
            if (x1 < FMAPX) for (int y = ylo; y <= yhi; ++y) scan_cell(minidx, x1, y, cix, ciy, best);
            int y0 = ciy - r, y1 = ciy + r;
            int xlo = max(x0 + 1, 0), xhi = min(x1 - 1, FMAPX - 1);
            if (y0 >= 0)    for (int x = xlo; x <= xhi; ++x) scan_cell(minidx, x, y0, cix, ciy, best);
            if (y1 < FMAPX) for (int x = xlo; x <= xhi; ++x) scan_cell(minidx, x, y1, cix, ciy, best);
        }
    }
    int ind = (int)(best & 0xffffffffull);
    float dminf = (float)(unsigned int)(best >> 32);

    ws->dminf[t]  = dminf;
    ws->factor[t] = fminf(__expf(-dminf * a) * 1e6f, 1.0f);

    // --- outputs: ret_boxes, inds, valid ---
    const float* g = gt + t * 8;
    float nx = (float)si[2 * ind];
    float ny = (float)si[2 * ind + 1];

    float* rb = out + 3 * N + t * 8;
    rb[0] = val ? (coord_x - nx) : 0.0f;
    rb[1] = val ? (coord_y - ny) : 0.0f;
    rb[2] = val ? g[2] : 0.0f;
    rb[3] = val ? logf(g[3]) : 0.0f;
    rb[4] = val ? logf(g[4]) : 0.0f;
    rb[5] = val ? logf(g[5]) : 0.0f;
    rb[6] = val ? cosf(g[6]) : 0.0f;
    rb[7] = val ? sinf(g[6]) : 0.0f;

    out[3 * N + 8 * K + t] = (float)ind;          // inds
    out[3 * N + 9 * K + t] = val ? 1.0f : 0.0f;   // valid
}

// ---------------------------------------------------------------------------
// 3. per-cell heatmap (object table in LDS, grouped by class)
// ---------------------------------------------------------------------------
__global__ __launch_bounds__(256) void k_heat(WS* ws) {
    __shared__ float cxL[KMAX], cyL[KMAX], aL[KMAX], dmL[KMAX], fcL[KMAX];
    __shared__ int segS[4];
    if (threadIdx.x < 4) segS[threadIdx.x] = ws->seg[threadIdx.x];
    __syncthreads();
    int ktot = segS[3];
    for (int i = threadIdx.x; i < ktot; i += 256) {
        int o = ws->list[i];
        cxL[i] = ws->cxi[o];
        cyL[i] = ws->cyi[o];
        aL[i]  = ws->a[o];
        dmL[i] = ws->dminf[o];
        fcL[i] = ws->factor[o];
    }
    __syncthreads();

    int c = blockIdx.x * 256 + threadIdx.x;
    if (c >= NCELLS) return;
    int cxi = c / FMAPX;
    float cx = (float)cxi;
    float cy = (float)(c - cxi * FMAPX);

    float m0 = 0.0f, m1 = 0.0f, m2 = 0.0f;
    int s1 = segS[1], s2 = segS[2];
    for (int i = 0; i < s1; i++) {
        float dx = cx - cxL[i], dy = cy - cyL[i];
        float dist = fmaf(dx, dx, dy * dy);
        float gv = __expf((dmL[i] - dist) * aL[i]) * fcL[i];
        m0 = fmaxf(m0, gv);
    }
    for (int i = s1; i < s2; i++) {
        float dx = cx - cxL[i], dy = cy - cyL[i];
        float dist = fmaf(dx, dx, dy * dy);
        float gv = __expf((dmL[i] - dist) * aL[i]) * fcL[i];
        m1 = fmaxf(m1, gv);
    }
    for (int i = s2; i < ktot; i++) {
        float dx = cx - cxL[i], dy = cy - cyL[i];
        float dist = fmaf(dx, dx, dy * dy);
        float gv = __expf((dmL[i] - dist) * aL[i]) * fcL[i];
        m2 = fmaxf(m2, gv);
    }
    ws->H[0][c] = m0;
    ws->H[1][c] = m1;
    ws->H[2][c] = m2;
}

// ---------------------------------------------------------------------------
// 4. gather per-voxel heatmap
// ---------------------------------------------------------------------------
__global__ __launch_bounds__(256) void k_gather(const int* __restrict__ si, int N,
                                                const WS* __restrict__ ws,
                                                float* __restrict__ out) {
    int n = blockIdx.x * 256 + threadIdx.x;
    if (n >= N) return;
    int2 v = ((const int2*)si)[n];
    int c = v.x * FMAPX + v.y;
    out[n]         = ws->H[0][c];
    out[N + n]     = ws->H[1][c];
    out[2 * N + n] = ws->H[2][c];
}

// ---------------------------------------------------------------------------
extern "C" void kernel_launch(void* const* d_in, const int* in_sizes, int n_in,
                              void* d_out, int out_size, void* d_ws, size_t ws_size,
                              hipStream_t stream) {
    const float* gt = (const float*)d_in[0];
    const int*   si = (const int*)d_in[1];
    int K = in_sizes[0] / 8;     // 500
    int N = in_sizes[1] / 2;     // 150000
    WS* ws = (WS*)d_ws;
    float* out = (float*)d_out;

    hipMemsetAsync(ws->minidx, 0x7f, NCELLS * sizeof(int), stream);
    hipLaunchKernelGGL(k_build_map, dim3((N + 255) / 256), dim3(256), 0, stream, si, N, ws);
    hipLaunchKernelGGL(k_obj_all, dim3(1), dim3(KMAX), 0, stream, gt, si, K, N, ws, out);
    hipLaunchKernelGGL(k_heat, dim3((NCELLS + 255) / 256), dim3(256), 0, stream, ws);
    hipLaunchKernelGGL(k_gather, dim3((N + 255) / 256), dim3(256), 0, stream, si, N, ws, out);
}